// Round 2
// baseline (485.223 us; speedup 1.0000x reference)
//
#include <hip/hip_runtime.h>
#include <hip/hip_bf16.h>
#include <stdint.h>

#define NHEADS 16
#define HDIM 80
#define CHUNK 2048
#define QSCALE 0.11180339887498949f   /* 80^-0.5 */
#define L2E 1.4426950408889634f

typedef __bf16 bf16x8 __attribute__((ext_vector_type(8)));
typedef float f32x4 __attribute__((ext_vector_type(4)));

__device__ __forceinline__ unsigned short f2bf(float f) {
  union { float f; unsigned u; } x; x.f = f;
  unsigned r = (x.u + 0x7fffu + ((x.u >> 16) & 1u)) >> 16;
  return (unsigned short)r;
}

__device__ __forceinline__ void gload16(const void* g, void* lds) {
  __builtin_amdgcn_global_load_lds((const __attribute__((address_space(1))) void*)g,
                                   (__attribute__((address_space(3))) void*)lds, 16, 0, 0);
}

/* ---------------- fp32 -> bf16 convert ---------------- */
__global__ __launch_bounds__(256) void cvt_f32_bf16(const float* __restrict__ in,
                                                    unsigned short* __restrict__ out, int n4) {
  int i = blockIdx.x * 256 + threadIdx.x;
  int stride = gridDim.x * 256;
  for (; i < n4; i += stride) {
    float4 v = reinterpret_cast<const float4*>(in)[i];
    ushort4 o;
    o.x = f2bf(v.x); o.y = f2bf(v.y); o.z = f2bf(v.z); o.w = f2bf(v.w);
    reinterpret_cast<ushort4*>(out)[i] = o;
  }
}

/* ---------------- m97-style bf16 GEMM: C = A * B^T + bias ----------------
   A: [M][K] bf16 row-major, B: [N][K] bf16 row-major.
   If Cf != nullptr: write fp32 to Cf, else write bf16 to C.
   Columns col < scaleN get (dot+bias)*scaleVal (used to pre-scale Q). */
__global__ __launch_bounds__(256) void gemm_bt(
    const unsigned short* __restrict__ A, const unsigned short* __restrict__ B,
    const float* __restrict__ bias, unsigned short* __restrict__ C,
    float* __restrict__ Cf,
    int M, int N, int K, int scaleN, float scaleVal)
{
  __shared__ unsigned short Ash[128 * 32];
  __shared__ unsigned short Bsh[128 * 32];
  const int tid = threadIdx.x;
  const int lane = tid & 63;
  const int w = tid >> 6;
  const int wr = w >> 1, wc = w & 1;
  const int l15 = lane & 15, lq = lane >> 4;
  const long bm = (long)blockIdx.y * 128;
  const long bn = (long)blockIdx.x * 128;

  f32x4 acc[4][4];
#pragma unroll
  for (int i = 0; i < 4; i++)
#pragma unroll
    for (int j = 0; j < 4; j++) acc[i][j] = f32x4{0.f, 0.f, 0.f, 0.f};

  const int srow = lane >> 2;        // 0..15
  const int scol = (lane & 3) * 8;   // k-element offset

  for (long k0 = 0; k0 < K; k0 += 32) {
    __syncthreads();
#pragma unroll
    for (int i = 0; i < 2; i++) {
      gload16(A + (bm + w * 32 + i * 16 + srow) * (long)K + k0 + scol,
              (char*)Ash + (w * 2 + i) * 1024);
      gload16(B + (bn + w * 32 + i * 16 + srow) * (long)K + k0 + scol,
              (char*)Bsh + (w * 2 + i) * 1024);
    }
    __syncthreads();
    bf16x8 af[4], bfr[4];
#pragma unroll
    for (int x = 0; x < 4; x++) {
      af[x]  = *reinterpret_cast<const bf16x8*>(Ash + (wr * 64 + x * 16 + l15) * 32 + lq * 8);
      bfr[x] = *reinterpret_cast<const bf16x8*>(Bsh + (wc * 64 + x * 16 + l15) * 32 + lq * 8);
    }
#pragma unroll
    for (int x = 0; x < 4; x++)
#pragma unroll
      for (int y = 0; y < 4; y++)
        acc[x][y] = __builtin_amdgcn_mfma_f32_16x16x32_bf16(af[x], bfr[y], acc[x][y], 0, 0, 0);
  }

#pragma unroll
  for (int x = 0; x < 4; x++) {
    long row0 = bm + wr * 64 + x * 16 + lq * 4;
#pragma unroll
    for (int y = 0; y < 4; y++) {
      int col = (int)bn + wc * 64 + y * 16 + l15;
      float bs = bias[col];
      float sc = (col < scaleN) ? scaleVal : 1.0f;
      if (Cf != nullptr) {
#pragma unroll
        for (int r = 0; r < 4; r++) {
          float v = (acc[x][y][r] + bs) * sc;
          Cf[(size_t)(row0 + r) * N + col] = v;
        }
      } else {
#pragma unroll
        for (int r = 0; r < 4; r++) {
          float v = (acc[x][y][r] + bs) * sc;
          C[(size_t)(row0 + r) * N + col] = f2bf(v);
        }
      }
    }
  }
}

/* ---------------- flash attention ----------------
   qkv: [8192][3840] bf16 (q pre-scaled by QSCALE), out: [8192][1280] bf16.
   grid: (16 q-tiles, 64 chunk*head), 256 threads = 4 waves, 32 q-rows/wave. */
__global__ __launch_bounds__(256) void attn_kernel(
    const unsigned short* __restrict__ qkv, unsigned short* __restrict__ out)
{
  __shared__ unsigned short Ksh[64 * 80];       // K tile, linear (global_load_lds)
  __shared__ unsigned short Vsh[80 * 72];       // V tile transposed, padded rows
  __shared__ unsigned short Psh[4][32 * 72];    // per-wave P tile, padded rows

  const int tid = threadIdx.x;
  const int lane = tid & 63;
  const int w = tid >> 6;
  const int l15 = lane & 15, lq = lane >> 4;
  const int ch = blockIdx.y >> 4;
  const int head = blockIdx.y & 15;
  const int qt = blockIdx.x;

  const size_t rs = 3840;  // qkv row stride (elements)
  const unsigned short* qbase = qkv + (size_t)(ch * CHUNK) * rs + head * HDIM;
  const unsigned short* kbase = qbase + 1280;
  const unsigned short* vbase = qbase + 2560;

  // Q fragments in registers (rows qr0..qr0+31 for this wave)
  const int qr0 = qt * 128 + w * 32;
  bf16x8 qa[2][2], qa2[2];
#pragma unroll
  for (int qf = 0; qf < 2; qf++) {
    const unsigned short* qrow = qbase + (size_t)(qr0 + qf * 16 + l15) * rs;
    qa[qf][0] = *reinterpret_cast<const bf16x8*>(qrow + lq * 8);
    qa[qf][1] = *reinterpret_cast<const bf16x8*>(qrow + 32 + lq * 8);
    if (lq < 2) qa2[qf] = *reinterpret_cast<const bf16x8*>(qrow + 64 + lq * 8);
    else        qa2[qf] = bf16x8{};
  }

  f32x4 acc[2][5];
#pragma unroll
  for (int qf = 0; qf < 2; qf++)
#pragma unroll
    for (int df = 0; df < 5; df++) acc[qf][df] = f32x4{0.f, 0.f, 0.f, 0.f};
  float mst[2][4], lst[2][4];
#pragma unroll
  for (int qf = 0; qf < 2; qf++)
#pragma unroll
    for (int r = 0; r < 4; r++) { mst[qf][r] = -1e30f; lst[qf][r] = 0.f; }

  for (int kt = 0; kt < CHUNK; kt += 64) {
    __syncthreads();
    // stage K tile (64 rows x 160B) via global_load_lds, linear
    for (int i = w; i < 10; i += 4) {
      int X = i * 1024 + lane * 16;
      int r = X / 160, db = X % 160;
      gload16((const char*)kbase + (size_t)(kt + r) * 7680 + db, (char*)Ksh + i * 1024);
    }
    // stage V tile transposed into padded [80][72]
    for (int u = tid; u < 640; u += 256) {
      int key = u & 63, dg = u >> 6;
      const unsigned short* src = vbase + (size_t)(kt + key) * rs + dg * 8;
      uint4 vv = *reinterpret_cast<const uint4*>(src);
      const unsigned short* pv = reinterpret_cast<const unsigned short*>(&vv);
      unsigned short* dst = &Vsh[(dg * 8) * 72 + key];
#pragma unroll
      for (int j = 0; j < 8; j++) dst[j * 72] = pv[j];
    }
    __syncthreads();

    // QK^T (d = 80 as 32+32+16-padded)
    f32x4 s[2][4];
#pragma unroll
    for (int qf = 0; qf < 2; qf++)
#pragma unroll
      for (int kf = 0; kf < 4; kf++) s[qf][kf] = f32x4{0.f, 0.f, 0.f, 0.f};
#pragma unroll
    for (int kf = 0; kf < 4; kf++) {
      const unsigned short* kr = Ksh + (kf * 16 + l15) * 80;
      bf16x8 kb0 = *reinterpret_cast<const bf16x8*>(kr + lq * 8);
      bf16x8 kb1 = *reinterpret_cast<const bf16x8*>(kr + 32 + lq * 8);
      bf16x8 kb2 = (lq < 2) ? *reinterpret_cast<const bf16x8*>(kr + 64 + lq * 8) : bf16x8{};
#pragma unroll
      for (int qf = 0; qf < 2; qf++) {
        s[qf][kf] = __builtin_amdgcn_mfma_f32_16x16x32_bf16(qa[qf][0], kb0, s[qf][kf], 0, 0, 0);
        s[qf][kf] = __builtin_amdgcn_mfma_f32_16x16x32_bf16(qa[qf][1], kb1, s[qf][kf], 0, 0, 0);
        s[qf][kf] = __builtin_amdgcn_mfma_f32_16x16x32_bf16(qa2[qf], kb2, s[qf][kf], 0, 0, 0);
      }
    }

    // online softmax + P write
#pragma unroll
    for (int qf = 0; qf < 2; qf++) {
      float mx[4], sm[4], alpha[4];
#pragma unroll
      for (int r = 0; r < 4; r++)
        mx[r] = fmaxf(fmaxf(s[qf][0][r], s[qf][1][r]), fmaxf(s[qf][2][r], s[qf][3][r]));
#pragma unroll
      for (int m = 1; m < 16; m <<= 1)
#pragma unroll
        for (int r = 0; r < 4; r++) mx[r] = fmaxf(mx[r], __shfl_xor(mx[r], m, 64));
#pragma unroll
      for (int r = 0; r < 4; r++) {
        float mnew = fmaxf(mst[qf][r], mx[r]);
        alpha[r] = exp2f((mst[qf][r] - mnew) * L2E);
        mst[qf][r] = mnew;
        sm[r] = 0.f;
      }
#pragma unroll
      for (int kf = 0; kf < 4; kf++)
#pragma unroll
        for (int r = 0; r < 4; r++) {
          float p = exp2f((s[qf][kf][r] - mst[qf][r]) * L2E);
          sm[r] += p;
          Psh[w][(qf * 16 + lq * 4 + r) * 72 + kf * 16 + l15] = f2bf(p);
        }
#pragma unroll
      for (int m = 1; m < 16; m <<= 1)
#pragma unroll
        for (int r = 0; r < 4; r++) sm[r] += __shfl_xor(sm[r], m, 64);
#pragma unroll
      for (int r = 0; r < 4; r++) lst[qf][r] = lst[qf][r] * alpha[r] + sm[r];
#pragma unroll
      for (int df = 0; df < 5; df++)
#pragma unroll
        for (int r = 0; r < 4; r++) acc[qf][df][r] *= alpha[r];
    }

    // PV: acc += P[32x64] * V[64x80]
#pragma unroll
    for (int ks = 0; ks < 2; ks++) {
      bf16x8 pa[2];
#pragma unroll
      for (int qf = 0; qf < 2; qf++)
        pa[qf] = *reinterpret_cast<const bf16x8*>(&Psh[w][(qf * 16 + l15) * 72 + ks * 32 + lq * 8]);
#pragma unroll
      for (int df = 0; df < 5; df++) {
        bf16x8 vb = *reinterpret_cast<const bf16x8*>(&Vsh[(df * 16 + l15) * 72 + ks * 32 + lq * 8]);
#pragma unroll
        for (int qf = 0; qf < 2; qf++)
          acc[qf][df] = __builtin_amdgcn_mfma_f32_16x16x32_bf16(pa[qf], vb, acc[qf][df], 0, 0, 0);
      }
    }
  }

  // epilogue: out = acc / l
  unsigned short* obase = out + (size_t)(ch * CHUNK) * 1280 + head * HDIM;
#pragma unroll
  for (int qf = 0; qf < 2; qf++)
#pragma unroll
    for (int df = 0; df < 5; df++) {
      int col = df * 16 + l15;
#pragma unroll
      for (int r = 0; r < 4; r++) {
        float v = acc[qf][df][r] / lst[qf][r];
        obase[(size_t)(qr0 + qf * 16 + lq * 4 + r) * 1280 + col] = f2bf(v);
      }
    }
}

extern "C" void kernel_launch(void* const* d_in, const int* in_sizes, int n_in,
                              void* d_out, int out_size, void* d_ws, size_t ws_size,
                              hipStream_t stream) {
  const float* hs    = (const float*)d_in[0];   // [8192][1280]
  const float* qkvw  = (const float*)d_in[2];   // [3840][1280]
  const float* qkvb  = (const float*)d_in[3];   // [3840]
  const float* projw = (const float*)d_in[4];   // [1280][1280]
  const float* projb = (const float*)d_in[5];   // [1280]

  char* ws = (char*)d_ws;
  unsigned short* hs_bf    = (unsigned short*)ws;                         // 20,971,520 B
  unsigned short* attn_bf  = hs_bf;                                       // alias (hs_bf dead after QKV gemm)
  unsigned short* qkvw_bf  = (unsigned short*)(ws + 20971520);            //  9,830,400 B
  unsigned short* projw_bf = (unsigned short*)(ws + 20971520 + 9830400);  //  3,276,800 B
  unsigned short* qkv_bf   = (unsigned short*)(ws + 20971520 + 9830400 + 3276800); // 62,914,560 B

  cvt_f32_bf16<<<2048, 256, 0, stream>>>(hs,    hs_bf,    8192 * 1280 / 4);
  cvt_f32_bf16<<<1024, 256, 0, stream>>>(qkvw,  qkvw_bf,  3840 * 1280 / 4);
  cvt_f32_bf16<<<512,  256, 0, stream>>>(projw, projw_bf, 1280 * 1280 / 4);

  // qkv = hs @ qkv_w^T + qkv_b ; q columns pre-scaled by 80^-0.5  (bf16 out)
  gemm_bt<<<dim3(30, 64), 256, 0, stream>>>(hs_bf, qkvw_bf, qkvb, qkv_bf, nullptr,
                                            8192, 3840, 1280, 1280, QSCALE);
  attn_kernel<<<dim3(16, 64), 256, 0, stream>>>(qkv_bf, attn_bf);
  // out = attn @ proj_w^T + proj_b   (fp32 out — reference output dtype is float32!)
  gemm_bt<<<dim3(10, 64), 256, 0, stream>>>(attn_bf, projw_bf, projb,
                                            nullptr, (float*)d_out,
                                            8192, 1280, 1280, 0, 1.0f);
}